// Round 3
// baseline (582.130 us; speedup 1.0000x reference)
//
#include <hip/hip_runtime.h>
#include <hip/hip_bf16.h>
#include <cstdint>
#include <cstddef>

#define S_LEN 2048
#define DM 1024
#define NEGV -1.0e9f

typedef __attribute__((ext_vector_type(8))) short bf16x8;
typedef __attribute__((ext_vector_type(4))) float f32x4;
typedef __attribute__((ext_vector_type(4))) unsigned short us4;
typedef __attribute__((ext_vector_type(4))) int i32x4;

__device__ __forceinline__ unsigned short f2bf(float f) {
  unsigned int u = __float_as_uint(f);
  unsigned int r = (u + 0x7fffu + ((u >> 16) & 1u)) >> 16;
  return (unsigned short)r;
}

__device__ __forceinline__ void async_copy16(const void* g, void* l) {
  __builtin_amdgcn_global_load_lds((const __attribute__((address_space(1))) void*)g,
                                   (__attribute__((address_space(3))) void*)l, 16, 0, 0);
}

// ---------------- f32 -> bf16 convert ----------------
__global__ void cvt_kernel(const float* __restrict__ src, unsigned short* __restrict__ dst, int n4) {
  int i = blockIdx.x * blockDim.x + threadIdx.x;
  if (i >= n4) return;
  const float4 v = reinterpret_cast<const float4*>(src)[i];
  us4 o;
  o[0] = f2bf(v.x); o[1] = f2bf(v.y); o[2] = f2bf(v.z); o[3] = f2bf(v.w);
  reinterpret_cast<us4*>(dst)[i] = o;
}

// ---------------- projection GEMM (unchanged, passed r1) ----------------
__global__ __launch_bounds__(256) void proj_gemm(
    const unsigned short* __restrict__ Xq, const unsigned short* __restrict__ Wqw,
    const float* __restrict__ bq, unsigned short* __restrict__ Cq,
    const unsigned short* __restrict__ Xk, const unsigned short* __restrict__ Wkw,
    const float* __restrict__ bk, unsigned short* __restrict__ Ck,
    const unsigned short* __restrict__ Xv, const unsigned short* __restrict__ Wvw,
    const float* __restrict__ bv, unsigned short* __restrict__ Cv) {
  const unsigned short* X; const unsigned short* W; const float* bias; unsigned short* C;
  if (blockIdx.z == 0)      { X = Xq; W = Wqw; bias = bq; C = Cq; }
  else if (blockIdx.z == 1) { X = Xk; W = Wkw; bias = bk; C = Ck; }
  else                      { X = Xv; W = Wvw; bias = bv; C = Cv; }

  __shared__ unsigned short Ab[128 * 64];
  __shared__ unsigned short Bb[128 * 64];

  const int t  = threadIdx.x;
  const int wv = t >> 6, l = t & 63;
  const int lr = l & 15, lg = l >> 4;
  const int wr = wv >> 1, wc = wv & 1;
  const int m0 = blockIdx.y * 128, n0 = blockIdx.x * 128;

  const f32x4 fz = {0.f, 0.f, 0.f, 0.f};
  f32x4 acc[4][4];
#pragma unroll
  for (int m = 0; m < 4; ++m)
#pragma unroll
    for (int n = 0; n < 4; ++n) acc[m][n] = fz;

  const int srow = t >> 3;
  const int sc16 = t & 7;

  for (int kt = 0; kt < 16; ++kt) {
    const int kb = kt * 64;
#pragma unroll
    for (int it = 0; it < 4; ++it) {
      const int row = it * 32 + srow;
      const int c16 = sc16 ^ (row & 7);
      const unsigned short* gA = X + (size_t)(m0 + row) * DM + kb + c16 * 8;
      const unsigned short* gB = W + (size_t)(n0 + row) * DM + kb + c16 * 8;
      async_copy16(gA, (char*)Ab + it * 4096 + wv * 1024);
      async_copy16(gB, (char*)Bb + it * 4096 + wv * 1024);
    }
    __syncthreads();
#pragma unroll
    for (int kk = 0; kk < 2; ++kk) {
      bf16x8 af[4], bfr[4];
      const int c16 = kk * 4 + lg;
      const int sw = (c16 ^ (lr & 7)) * 16;
#pragma unroll
      for (int m = 0; m < 4; ++m) {
        const int row = wr * 64 + m * 16 + lr;
        af[m] = *(const bf16x8*)((const char*)Ab + row * 128 + sw);
      }
#pragma unroll
      for (int n = 0; n < 4; ++n) {
        const int row = wc * 64 + n * 16 + lr;
        bfr[n] = *(const bf16x8*)((const char*)Bb + row * 128 + sw);
      }
#pragma unroll
      for (int m = 0; m < 4; ++m)
#pragma unroll
        for (int n = 0; n < 4; ++n)
          acc[m][n] = __builtin_amdgcn_mfma_f32_16x16x32_bf16(af[m], bfr[n], acc[m][n], 0, 0, 0);
    }
    __syncthreads();
  }

#pragma unroll
  for (int n = 0; n < 4; ++n) {
    const int ccol = n0 + wc * 64 + n * 16 + lr;
    const float bb = bias[ccol];
#pragma unroll
    for (int m = 0; m < 4; ++m) {
      const int crow0 = m0 + wr * 64 + m * 16 + lg * 4;
#pragma unroll
      for (int j = 0; j < 4; ++j)
        C[(size_t)(crow0 + j) * DM + ccol] = f2bf(acc[m][n][j] + bb);
    }
  }
}

// ---------------- V transpose: [4096,1024] -> [1024,4096] ----------------
__global__ void transpose_bf(const unsigned short* __restrict__ src, unsigned short* __restrict__ dst) {
  __shared__ unsigned short tb[32][33];
  const int x = threadIdx.x & 31, y = threadIdx.x >> 5;
  const int bx = blockIdx.x, by = blockIdx.y;
#pragma unroll
  for (int r = 0; r < 32; r += 8)
    tb[r + y][x] = src[(size_t)(by * 32 + r + y) * DM + bx * 32 + x];
  __syncthreads();
#pragma unroll
  for (int r = 0; r < 32; r += 8)
    dst[(size_t)(bx * 32 + r + y) * 4096 + by * 32 + x] = tb[x][r + y];
}

// ---------------- fused attention v2.1: wave-autonomous two-pass ----------------
// FIX vs v2: Vt row stride is 2*S_LEN=4096 (was wrongly 4*S_LEN=8192).
__global__ __launch_bounds__(256) void attn2_kernel(
    const unsigned short* __restrict__ Qp, const unsigned short* __restrict__ Kp,
    const unsigned short* __restrict__ Vt, const int* __restrict__ mask,
    float* __restrict__ outp, float* __restrict__ attnp) {
  __shared__ unsigned short Pb[4][16 * 40];  // per-wave repack, row stride 40 shorts

  int bx = blockIdx.x;
  bx = ((bx & 7) << 7) | (bx >> 3);  // bijective XCD swizzle (1024 % 8 == 0)
  const int w = threadIdx.x >> 6, l = threadIdx.x & 63;
  const int t = (bx << 2) | w;       // 4 waves of a block share (b,qt)
  const int h = t & 15, qt = (t >> 4) & 127, b = t >> 11;
  const int q0 = qt << 4;
  const int lr = l & 15, lg = l >> 4;

  const f32x4 fz = {0.f, 0.f, 0.f, 0.f};
  const float scale = 0.125f;

  // Q as B-operand: lane holds Q[q0+lr][lg*8..+7] of this head
  const unsigned short* Qh = Qp + (size_t)(b * S_LEN + q0 + lr) * DM + h * 64;
  const bf16x8 qf0 = *(const bf16x8*)(Qh + lg * 8);
  const bf16x8 qf1 = *(const bf16x8*)(Qh + 32 + lg * 8);

  const unsigned short* Kh = Kp + (size_t)b * S_LEN * DM + h * 64;
  const int* mrow = mask + (size_t)(b * S_LEN + q0 + lr) * S_LEN;

  // ---- pass 1: exp row-sum (swapped QK: C col=lr=query, row=lg*4+j=key) ----
  float rs = 0.f;
#pragma unroll 2
  for (int kb = 0; kb < 128; ++kb) {
    const unsigned short* Kr = Kh + (size_t)(kb * 16 + lr) * DM;
    const bf16x8 ka0 = *(const bf16x8*)(Kr + lg * 8);
    const bf16x8 ka1 = *(const bf16x8*)(Kr + 32 + lg * 8);
    const i32x4 m4 = *(const i32x4*)(mrow + kb * 16 + lg * 4);
    f32x4 sc = fz;
    sc = __builtin_amdgcn_mfma_f32_16x16x32_bf16(ka0, qf0, sc, 0, 0, 0);
    sc = __builtin_amdgcn_mfma_f32_16x16x32_bf16(ka1, qf1, sc, 0, 0, 0);
#pragma unroll
    for (int j = 0; j < 4; ++j) {
      const float sv = (m4[j] == 0) ? NEGV : sc[j] * scale;
      rs += __expf(sv);
    }
  }
  rs += __shfl_xor(rs, 16, 64);
  rs += __shfl_xor(rs, 32, 64);
  const float rinv = 1.0f / rs;

  // ---- pass 2: normalize + attn store + P repack + PV ----
  float* attnq = attnp + (size_t)((b * 16 + h) * S_LEN + q0 + lr) * S_LEN;
  unsigned short* pbw = &Pb[w][0];
  const unsigned short* Vh = Vt + (size_t)(h * 64) * (2 * S_LEN) + b * S_LEN;

  f32x4 oacc[4];
#pragma unroll
  for (int n = 0; n < 4; ++n) oacc[n] = fz;

  for (int kb2 = 0; kb2 < 64; ++kb2) {
    const int k0 = kb2 * 32;
    f32x4 sc0 = fz, sc1 = fz;
    {
      const unsigned short* Kr = Kh + (size_t)(k0 + lr) * DM;
      const bf16x8 a0 = *(const bf16x8*)(Kr + lg * 8);
      const bf16x8 a1 = *(const bf16x8*)(Kr + 32 + lg * 8);
      sc0 = __builtin_amdgcn_mfma_f32_16x16x32_bf16(a0, qf0, sc0, 0, 0, 0);
      sc0 = __builtin_amdgcn_mfma_f32_16x16x32_bf16(a1, qf1, sc0, 0, 0, 0);
    }
    {
      const unsigned short* Kr = Kh + (size_t)(k0 + 16 + lr) * DM;
      const bf16x8 a0 = *(const bf16x8*)(Kr + lg * 8);
      const bf16x8 a1 = *(const bf16x8*)(Kr + 32 + lg * 8);
      sc1 = __builtin_amdgcn_mfma_f32_16x16x32_bf16(a0, qf0, sc1, 0, 0, 0);
      sc1 = __builtin_amdgcn_mfma_f32_16x16x32_bf16(a1, qf1, sc1, 0, 0, 0);
    }
    const i32x4 m0 = *(const i32x4*)(mrow + k0 + lg * 4);
    const i32x4 m1 = *(const i32x4*)(mrow + k0 + 16 + lg * 4);

    float4 p0, p1;
    us4 w0, w1;
    {
      float pv;
      pv = __expf((m0[0] == 0) ? NEGV : sc0[0] * scale) * rinv; p0.x = pv; w0[0] = f2bf(pv);
      pv = __expf((m0[1] == 0) ? NEGV : sc0[1] * scale) * rinv; p0.y = pv; w0[1] = f2bf(pv);
      pv = __expf((m0[2] == 0) ? NEGV : sc0[2] * scale) * rinv; p0.z = pv; w0[2] = f2bf(pv);
      pv = __expf((m0[3] == 0) ? NEGV : sc0[3] * scale) * rinv; p0.w = pv; w0[3] = f2bf(pv);
      pv = __expf((m1[0] == 0) ? NEGV : sc1[0] * scale) * rinv; p1.x = pv; w1[0] = f2bf(pv);
      pv = __expf((m1[1] == 0) ? NEGV : sc1[1] * scale) * rinv; p1.y = pv; w1[1] = f2bf(pv);
      pv = __expf((m1[2] == 0) ? NEGV : sc1[2] * scale) * rinv; p1.z = pv; w1[2] = f2bf(pv);
      pv = __expf((m1[3] == 0) ? NEGV : sc1[3] * scale) * rinv; p1.w = pv; w1[3] = f2bf(pv);
    }
    // attn stores: per (lr,lg-group) 16 consecutive f32 = 64B segments
    *(float4*)(attnq + k0 + lg * 4) = p0;
    *(float4*)(attnq + k0 + 16 + lg * 4) = p1;

    // wave-private LDS repack: P[q=lr][k-in-chunk]
    *(us4*)(pbw + lr * 40 + lg * 4) = w0;
    *(us4*)(pbw + lr * 40 + 16 + lg * 4) = w1;
    asm volatile("s_waitcnt lgkmcnt(0)" ::: "memory");
    __builtin_amdgcn_sched_barrier(0);
    const bf16x8 pa = *(const bf16x8*)(pbw + lr * 40 + lg * 8);

#pragma unroll
    for (int n = 0; n < 4; ++n) {
      const bf16x8 vb = *(const bf16x8*)(Vh + (size_t)(n * 16 + lr) * (2 * S_LEN) + k0 + lg * 8);
      oacc[n] = __builtin_amdgcn_mfma_f32_16x16x32_bf16(pa, vb, oacc[n], 0, 0, 0);
    }
    asm volatile("s_waitcnt lgkmcnt(0)" ::: "memory");
    __builtin_amdgcn_sched_barrier(0);
  }

  // out: C[q=lg*4+j][d=n*16+lr]
  float* orow = outp + (size_t)(b * S_LEN + q0) * DM + h * 64;
#pragma unroll
  for (int n = 0; n < 4; ++n)
#pragma unroll
    for (int j = 0; j < 4; ++j)
      orow[(size_t)(lg * 4 + j) * DM + n * 16 + lr] = oacc[n][j];
}

extern "C" void kernel_launch(void* const* d_in, const int* in_sizes, int n_in,
                              void* d_out, int out_size, void* d_ws, size_t ws_size,
                              hipStream_t stream) {
  const float* query = (const float*)d_in[0];
  const float* key_  = (const float*)d_in[1];
  const float* value = (const float*)d_in[2];
  const int*   mask  = (const int*)d_in[3];
  const float* Wq = (const float*)d_in[4];
  const float* bq = (const float*)d_in[5];
  const float* Wk = (const float*)d_in[6];
  const float* bk = (const float*)d_in[7];
  const float* Wv = (const float*)d_in[8];
  const float* bv = (const float*)d_in[9];

  float* outp  = (float*)d_out;
  float* attnp = outp + (size_t)2 * S_LEN * DM;

  unsigned short* ws  = (unsigned short*)d_ws;
  unsigned short* qbf = ws;
  unsigned short* kbf = qbf + 4194304;
  unsigned short* vbf = kbf + 4194304;
  unsigned short* wqb = vbf + 4194304;
  unsigned short* wkb = wqb + 1048576;
  unsigned short* wvb = wkb + 1048576;
  unsigned short* qp  = wvb + 1048576;
  unsigned short* kp  = qp + 4194304;
  unsigned short* vp  = kp + 4194304;
  unsigned short* vt  = vp + 4194304;

  cvt_kernel<<<4096, 256, 0, stream>>>(query, qbf, 1048576);
  cvt_kernel<<<4096, 256, 0, stream>>>(key_,  kbf, 1048576);
  cvt_kernel<<<4096, 256, 0, stream>>>(value, vbf, 1048576);
  cvt_kernel<<<1024, 256, 0, stream>>>(Wq, wqb, 262144);
  cvt_kernel<<<1024, 256, 0, stream>>>(Wk, wkb, 262144);
  cvt_kernel<<<1024, 256, 0, stream>>>(Wv, wvb, 262144);

  proj_gemm<<<dim3(8, 32, 3), 256, 0, stream>>>(qbf, wqb, bq, qp,
                                                kbf, wkb, bk, kp,
                                                vbf, wvb, bv, vp);
  transpose_bf<<<dim3(32, 128), 256, 0, stream>>>(vp, vt);
  attn2_kernel<<<1024, 256, 0, stream>>>(qp, kp, vt, mask, outp, attnp);
}